// Round 5
// baseline (353.168 us; speedup 1.0000x reference)
//
#include <hip/hip_runtime.h>
#include <hip/hip_bf16.h>

// B=4, S=1024, H=12, D=64, DIM=768, L=512, NNZ=2048
// qkv = hid(2048x768) @ W(2304x768)^T + b ; only rows q<512 / keys k<512 alive.
// scores = QK^T/8 + bias[b,h,q,k<512]; softmax without max-subtract is exact here
// (live-key scores are O(+-3.5): exp cannot overflow; masked keys excluded entirely).
//
// ROUND 5 = RETRY of round-4 DIAGNOSTIC (round 4 died to container infra, not
// the kernel). Kernels identical to round 3; each launched TWICE (idempotent).
// dur_R5 - dur_R3 = (gemm + attn) exactly -- separates harness re-poison
// floor (H1: delta ~35us) from slow-kernel hypothesis (H2: delta ~130us).

typedef __attribute__((ext_vector_type(8))) __bf16 bf16x8;
typedef __attribute__((ext_vector_type(4))) __bf16 bf16x4;
typedef __attribute__((ext_vector_type(4))) float  f32x4;

static __device__ __forceinline__ __bf16 tobf(float x) { return (__bf16)x; }

// ---------------- kernel 1: QKV GEMM, fused f32->bf16 staging ----------------
__global__ __launch_bounds__(256) void qkv_gemm(
    const float* __restrict__ hid,    // [2048][768] f32
    const float* __restrict__ W,      // [2304][768] f32
    const float* __restrict__ qb,     // [2304]
    __bf16* __restrict__ Qb, __bf16* __restrict__ Kb, __bf16* __restrict__ Vt)
{
    __shared__ char lds[2][24 * 1024];   // per buf: A[128][128B] @0, B[64][128B] @16384

    const int tid = threadIdx.x, lane = tid & 63, wave = tid >> 6;
    const int lo = lane & 15, hi = lane >> 4;
    const int wr = wave >> 1, wc = wave & 1;

    int flat = blockIdx.x;
    flat = (flat & 7) * 72 + (flat >> 3);          // XCD-contiguous chunks (576%8==0)
    const int f0 = (flat % 36) * 64;               // feature tile
    const int r0 = (flat / 36) * 128;              // token-row tile

    const int srow = tid >> 3;                     // 0..31
    const int kel  = (tid & 7) * 8;                // f32 element offset within K-tile

    const float* abase = hid + (size_t)(r0 + srow) * 768 + kel;
    const float* bbase = W   + (size_t)(f0 + srow) * 768 + kel;

    float4 sa[6][2];
    auto LOADT = [&](int kt) {
        const int k0 = kt * 64;
#pragma unroll
        for (int p = 0; p < 4; ++p) {
            const float* a = abase + (size_t)p * 32 * 768 + k0;
            sa[p][0] = *reinterpret_cast<const float4*>(a);
            sa[p][1] = *reinterpret_cast<const float4*>(a + 4);
        }
#pragma unroll
        for (int p = 0; p < 2; ++p) {
            const float* bsrc = bbase + (size_t)p * 32 * 768 + k0;
            sa[4 + p][0] = *reinterpret_cast<const float4*>(bsrc);
            sa[4 + p][1] = *reinterpret_cast<const float4*>(bsrc + 4);
        }
    };
    auto STORET = [&](int buf) {
#pragma unroll
        for (int s = 0; s < 6; ++s) {
            const int row = (s < 4) ? s * 32 + srow : (s - 4) * 32 + srow;
            const int off = (s < 4) ? 0 : 16384;
            float4 x = sa[s][0], y = sa[s][1];
            bf16x8 o = { tobf(x.x), tobf(x.y), tobf(x.z), tobf(x.w),
                         tobf(y.x), tobf(y.y), tobf(y.z), tobf(y.w) };
            *reinterpret_cast<bf16x8*>(&lds[buf][off + row * 128 + ((kel * 2) ^ ((row & 7) << 4))]) = o;
        }
    };

    f32x4 acc[4][2] = {};
    LOADT(0); STORET(0);
    __syncthreads();

#pragma unroll 1
    for (int kt = 0; kt < 12; ++kt) {
        if (kt < 11) LOADT(kt + 1);          // global loads in flight during MFMA
        const char* L = lds[kt & 1];
#pragma unroll
        for (int ks = 0; ks < 2; ++ks) {
            bf16x8 bfrag[2];
#pragma unroll
            for (int fn = 0; fn < 2; ++fn) {
                int row = wc * 32 + fn * 16 + lo;
                bfrag[fn] = *reinterpret_cast<const bf16x8*>(
                    L + 16384 + row * 128 + ((ks * 64 + hi * 16) ^ ((row & 7) << 4)));
            }
#pragma unroll
            for (int fm = 0; fm < 4; ++fm) {
                int row = wr * 64 + fm * 16 + lo;
                bf16x8 af = *reinterpret_cast<const bf16x8*>(
                    L + row * 128 + ((ks * 64 + hi * 16) ^ ((row & 7) << 4)));
                acc[fm][0] = __builtin_amdgcn_mfma_f32_16x16x32_bf16(af, bfrag[0], acc[fm][0], 0, 0, 0);
                acc[fm][1] = __builtin_amdgcn_mfma_f32_16x16x32_bf16(af, bfrag[1], acc[fm][1], 0, 0, 0);
            }
        }
        if (kt < 11) STORET((kt & 1) ^ 1);   // write other buffer; one barrier/iter
        __syncthreads();
    }

    // epilogue: +bias, Q*=0.125, scatter
#pragma unroll
    for (int fn = 0; fn < 2; ++fn) {
        int m = f0 + wc * 32 + fn * 16 + lo;   // feature 0..2303
        float bv = qb[m];
        int sel = m / 768;                     // 0=Q 1=K 2=V
        int mm  = m - sel * 768;
        int hh  = mm >> 6, d = mm & 63;
        float scale = (sel == 0) ? 0.125f : 1.0f;
#pragma unroll
        for (int fm = 0; fm < 4; ++fm) {
            int t0 = r0 + wr * 64 + fm * 16 + hi * 4;   // 4 consecutive tokens, no 512-cross
            int b  = t0 >> 9, q = t0 & 511;
            int bh = b * 12 + hh;
            float v[4];
#pragma unroll
            for (int j = 0; j < 4; ++j) v[j] = (acc[fm][fn][j] + bv) * scale;
            if (sel == 2) {
                bf16x4 pv = { tobf(v[0]), tobf(v[1]), tobf(v[2]), tobf(v[3]) };
                *reinterpret_cast<bf16x4*>(&Vt[((size_t)bh * 64 + d) * 512 + q]) = pv;
            } else {
                __bf16* dst = (sel == 0) ? Qb : Kb;
#pragma unroll
                for (int j = 0; j < 4; ++j)
                    dst[((size_t)bh * 512 + q + j) * 64 + d] = tobf(v[j]);
            }
        }
    }
}

// ---------------- kernel 2: attention, pipelined, registers-only scores -----
__global__ __launch_bounds__(256) void attn_kernel(
    const __bf16* __restrict__ Qb, const __bf16* __restrict__ Kb,
    const __bf16* __restrict__ Vt, const float* __restrict__ bias,
    float* __restrict__ out)
{
    __shared__ __bf16 P[4][16][40];       // per-wave P slab, rows padded to 80B
    __shared__ float  Obuf[2][16][68];
    __shared__ float  Lbuf[2][16];

    const int tid = threadIdx.x, lane = tid & 63, wave = tid >> 6;
    const int lo = lane & 15, hi = lane >> 4;
    const int qt = wave >> 1, kp = wave & 1;

    int flat = blockIdx.x;
    flat = (flat & 7) * 96 + (flat >> 3);   // XCD swizzle
    const int bh = flat >> 4, qtile = flat & 15;
    const int b = bh / 12, hd = bh % 12;
    const int q0 = qtile * 32 + qt * 16;

    const __bf16* Qp = Qb + ((size_t)bh * 512 + q0) * 64;
    bf16x8 qf0 = *reinterpret_cast<const bf16x8*>(Qp + lo * 64 + hi * 8);
    bf16x8 qf1 = *reinterpret_cast<const bf16x8*>(Qp + lo * 64 + 32 + hi * 8);

    const __bf16* Kbh = Kb + (size_t)bh * 512 * 64;
    const __bf16* Vbh = Vt + (size_t)bh * 64 * 512;
    const float*  bp  = bias + ((size_t)bh * 1024 + q0) * 1024;

    f32x4 c0[2], c1[2];
    bf16x8 kf[2][4], vf[2][4];
    auto LOADC = [&](int kc, int s) {
        const int k0 = kp * 256 + kc * 32;
#pragma unroll
        for (int j = 0; j < 4; ++j) {
            const float* r = bp + (size_t)(hi * 4 + j) * 1024 + k0;
            c0[s][j] = r[lo];
            c1[s][j] = r[16 + lo];
        }
        const __bf16* kr = Kbh + (size_t)(k0 + lo) * 64 + hi * 8;
        kf[s][0] = *reinterpret_cast<const bf16x8*>(kr);
        kf[s][1] = *reinterpret_cast<const bf16x8*>(kr + 32);
        kf[s][2] = *reinterpret_cast<const bf16x8*>(kr + 16 * 64);
        kf[s][3] = *reinterpret_cast<const bf16x8*>(kr + 16 * 64 + 32);
#pragma unroll
        for (int dt = 0; dt < 4; ++dt)
            vf[s][dt] = *reinterpret_cast<const bf16x8*>(
                Vbh + (size_t)(dt * 16 + lo) * 512 + k0 + hi * 8);
    };

    f32x4 oacc[4] = {};
    float lsum[4] = {0.f, 0.f, 0.f, 0.f};
    __bf16* Pw = &P[wave][0][0];

    LOADC(0, 0);
#pragma unroll
    for (int kc = 0; kc < 8; ++kc) {
        const int s = kc & 1;
        if (kc < 7) LOADC(kc + 1, s ^ 1);   // next chunk's bias/K/V in flight
        __builtin_amdgcn_s_setprio(1);
        f32x4 s0 = __builtin_amdgcn_mfma_f32_16x16x32_bf16(qf0, kf[s][0], c0[s], 0, 0, 0);
        s0       = __builtin_amdgcn_mfma_f32_16x16x32_bf16(qf1, kf[s][1], s0, 0, 0, 0);
        f32x4 s1 = __builtin_amdgcn_mfma_f32_16x16x32_bf16(qf0, kf[s][2], c1[s], 0, 0, 0);
        s1       = __builtin_amdgcn_mfma_f32_16x16x32_bf16(qf1, kf[s][3], s1, 0, 0, 0);
        __builtin_amdgcn_s_setprio(0);

#pragma unroll
        for (int j = 0; j < 4; ++j) {
            float p0 = __expf(s0[j]), p1 = __expf(s1[j]);
            lsum[j] += p0 + p1;
            Pw[(hi * 4 + j) * 40 + lo]      = tobf(p0);
            Pw[(hi * 4 + j) * 40 + 16 + lo] = tobf(p1);
        }
        bf16x8 pf = *reinterpret_cast<const bf16x8*>(Pw + lo * 40 + hi * 8);
        __builtin_amdgcn_s_setprio(1);
#pragma unroll
        for (int dt = 0; dt < 4; ++dt)
            oacc[dt] = __builtin_amdgcn_mfma_f32_16x16x32_bf16(pf, vf[s][dt], oacc[dt], 0, 0, 0);
        __builtin_amdgcn_s_setprio(0);
    }

    // reduce partial row-sums across 16-lane column groups
#pragma unroll
    for (int j = 0; j < 4; ++j) {
        float s = lsum[j];
        s += __shfl_xor(s, 1, 64); s += __shfl_xor(s, 2, 64);
        s += __shfl_xor(s, 4, 64); s += __shfl_xor(s, 8, 64);
        lsum[j] = s;
    }

    if (kp == 1) {
#pragma unroll
        for (int dt = 0; dt < 4; ++dt)
#pragma unroll
            for (int j = 0; j < 4; ++j)
                Obuf[qt][hi * 4 + j][dt * 16 + lo] = oacc[dt][j];
        if (lo == 0) {
#pragma unroll
            for (int j = 0; j < 4; ++j) Lbuf[qt][hi * 4 + j] = lsum[j];
        }
    }
    __syncthreads();
    if (kp == 0) {
#pragma unroll
        for (int j = 0; j < 4; ++j) {
            float inv = 1.0f / (lsum[j] + Lbuf[qt][hi * 4 + j]);
            int q = q0 + hi * 4 + j;
            float* op = out + (size_t)(b * 512 + q) * 768 + hd * 64;
#pragma unroll
            for (int dt = 0; dt < 4; ++dt)
                op[dt * 16 + lo] = (oacc[dt][j] + Obuf[qt][hi * 4 + j][dt * 16 + lo]) * inv;
        }
    }
}

// ---------------------------------------------------------------------------
extern "C" void kernel_launch(void* const* d_in, const int* in_sizes, int n_in,
                              void* d_out, int out_size, void* d_ws, size_t ws_size,
                              hipStream_t stream) {
    const float* hid  = (const float*)d_in[0];   // (2048,768) f32
    const float* W    = (const float*)d_in[1];   // (2304,768) f32
    const float* qb   = (const float*)d_in[2];   // (2304,) f32
    const float* bias = (const float*)d_in[3];   // (4,12,1024,1024) f32
    float* out = (float*)d_out;                  // (2048,768) f32

    char* ws = (char*)d_ws;
    __bf16* Qb = (__bf16*)(ws);                  // 3,145,728 B (pre-scaled by 1/8)
    __bf16* Kb = (__bf16*)(ws + 3145728);        // 3,145,728 B
    __bf16* Vt = (__bf16*)(ws + 6291456);        // 3,145,728 B [bh][64][512]

    // DIAGNOSTIC: each kernel launched twice (idempotent).
    // dur_R5 - dur_R3 = gemm_time + attn_time.
    qkv_gemm<<<576, 256, 0, stream>>>(hid, W, qb, Qb, Kb, Vt);
    attn_kernel<<<768, 256, 0, stream>>>(Qb, Kb, Vt, bias, out);
    qkv_gemm<<<576, 256, 0, stream>>>(hid, W, qb, Qb, Kb, Vt);
    attn_kernel<<<768, 256, 0, stream>>>(Qb, Kb, Vt, bias, out);
}

// Round 6
// 296.229 us; speedup vs baseline: 1.1922x; 1.1922x over previous
//
#include <hip/hip_runtime.h>
#include <hip/hip_bf16.h>

// B=4, S=1024, H=12, D=64, DIM=768, L=512, NNZ=2048
// qkv = hid(2048x768) @ W(2304x768)^T + b ; only rows q<512 / keys k<512 alive.
// scores = QK^T/8 + bias[b,h,q,k<512]; softmax without max-subtract is exact here
// (live-key scores are O(+-3.5): exp cannot overflow; masked keys excluded).
//
// R6: diagnostics (R5) showed gemm+attn = 55us combined; harness floor ~243us.
// This round: cvt->bf16 + 128x128 gemm tile (halves + localizes L2/L3 traffic),
// attn bias prefetch 3-deep. Single launches restored.

typedef __attribute__((ext_vector_type(8))) __bf16 bf16x8;
typedef __attribute__((ext_vector_type(4))) __bf16 bf16x4;
typedef __attribute__((ext_vector_type(4))) float  f32x4;

static __device__ __forceinline__ __bf16 tobf(float x) { return (__bf16)x; }

// ---------------- kernel 0: f32 -> bf16 pre-convert (hid | W) ----------------
__global__ __launch_bounds__(256) void cvt_bf16(const float* __restrict__ hid,
                                                const float* __restrict__ W,
                                                __bf16* __restrict__ hidB,
                                                __bf16* __restrict__ WB)
{
    int i = blockIdx.x * 256 + threadIdx.x;   // octet index, exactly 417792 threads
    const float* src; __bf16* dst; int off;
    if (i < 196608) { src = hid; dst = hidB; off = i * 8; }
    else            { src = W;   dst = WB;   off = (i - 196608) * 8; }
    float4 a = *reinterpret_cast<const float4*>(src + off);
    float4 b = *reinterpret_cast<const float4*>(src + off + 4);
    bf16x8 o = { tobf(a.x), tobf(a.y), tobf(a.z), tobf(a.w),
                 tobf(b.x), tobf(b.y), tobf(b.z), tobf(b.w) };
    *reinterpret_cast<bf16x8*>(dst + off) = o;
}

// ---------------- kernel 1: QKV GEMM, tile 128(rows) x 128(features), BK=64 --
// 288 blocks = 18 f-tiles x 16 r-tiles, XCD-swizzled (per-XCD chunk = 36 blocks
// = full A panel + 2-3 B panels -> 4MB L2 resident). 4 waves (2x2), LDS
// double-buffered (2 x 32KB), one barrier per K-step, reg prefetch.
__global__ __launch_bounds__(256) void qkv_gemm(
    const __bf16* __restrict__ hidB,  // [2048][768]
    const __bf16* __restrict__ WB,    // [2304][768]
    const float*  __restrict__ qb,    // [2304]
    __bf16* __restrict__ Qb, __bf16* __restrict__ Kb, __bf16* __restrict__ Vt)
{
    __shared__ char lds[2][32 * 1024];   // per buf: A[128][128B] @0, B[128][128B] @16384

    const int tid = threadIdx.x, lane = tid & 63, wave = tid >> 6;
    const int lo = lane & 15, hi = lane >> 4;
    const int wr = wave >> 1, wc = wave & 1;

    int flat = blockIdx.x;
    flat = (flat & 7) * 36 + (flat >> 3);          // XCD-contiguous chunks (288%8==0)
    const int f0 = (flat >> 4) * 128;              // feature tile (18)
    const int r0 = (flat & 15) * 128;              // token-row tile (16)

    const int srow = tid >> 3;                     // 0..31
    const int kel  = (tid & 7) * 8;                // element offset within K-tile (64)

    const __bf16* abase = hidB + (size_t)(r0 + srow) * 768 + kel;
    const __bf16* bbase = WB   + (size_t)(f0 + srow) * 768 + kel;

    bf16x8 st[8];
    auto LOADT = [&](int kt) {
        const int k0 = kt * 64;
#pragma unroll
        for (int p = 0; p < 4; ++p)
            st[p]     = *reinterpret_cast<const bf16x8*>(abase + (size_t)p * 32 * 768 + k0);
#pragma unroll
        for (int p = 0; p < 4; ++p)
            st[4 + p] = *reinterpret_cast<const bf16x8*>(bbase + (size_t)p * 32 * 768 + k0);
    };
    auto STORET = [&](int buf) {
#pragma unroll
        for (int s = 0; s < 8; ++s) {
            const int row = (s & 3) * 32 + srow;
            const int off = (s < 4) ? 0 : 16384;
            *reinterpret_cast<bf16x8*>(
                &lds[buf][off + row * 128 + ((kel * 2) ^ ((row & 7) << 4))]) = st[s];
        }
    };

    f32x4 acc[4][4] = {};
    LOADT(0); STORET(0);
    __syncthreads();

#pragma unroll 1
    for (int kt = 0; kt < 12; ++kt) {
        if (kt < 11) LOADT(kt + 1);          // next K-tile in flight during MFMA
        const char* L = lds[kt & 1];
#pragma unroll
        for (int ks = 0; ks < 2; ++ks) {
            bf16x8 bfrag[4];
#pragma unroll
            for (int fn = 0; fn < 4; ++fn) {
                int row = wc * 64 + fn * 16 + lo;
                bfrag[fn] = *reinterpret_cast<const bf16x8*>(
                    L + 16384 + row * 128 + ((ks * 64 + hi * 16) ^ ((row & 7) << 4)));
            }
#pragma unroll
            for (int fm = 0; fm < 4; ++fm) {
                int row = wr * 64 + fm * 16 + lo;
                bf16x8 af = *reinterpret_cast<const bf16x8*>(
                    L + row * 128 + ((ks * 64 + hi * 16) ^ ((row & 7) << 4)));
#pragma unroll
                for (int fn = 0; fn < 4; ++fn)
                    acc[fm][fn] = __builtin_amdgcn_mfma_f32_16x16x32_bf16(af, bfrag[fn], acc[fm][fn], 0, 0, 0);
            }
        }
        if (kt < 11) STORET((kt & 1) ^ 1);   // fill other buffer; one barrier/iter
        __syncthreads();
    }

    // epilogue: +bias, Q*=0.125, scatter
#pragma unroll
    for (int fn = 0; fn < 4; ++fn) {
        int m = f0 + wc * 64 + fn * 16 + lo;   // feature 0..2303
        float bv = qb[m];
        int sel = m / 768;                     // 0=Q 1=K 2=V
        int mm  = m - sel * 768;
        int hh  = mm >> 6, d = mm & 63;
        float scale = (sel == 0) ? 0.125f : 1.0f;
#pragma unroll
        for (int fm = 0; fm < 4; ++fm) {
            int t0 = r0 + wr * 64 + fm * 16 + hi * 4;   // 4 consecutive tokens, no 512-cross
            int b  = t0 >> 9, q = t0 & 511;
            int bh = b * 12 + hh;
            float v[4];
#pragma unroll
            for (int j = 0; j < 4; ++j) v[j] = (acc[fm][fn][j] + bv) * scale;
            if (sel == 2) {
                bf16x4 pv = { tobf(v[0]), tobf(v[1]), tobf(v[2]), tobf(v[3]) };
                *reinterpret_cast<bf16x4*>(&Vt[((size_t)bh * 64 + d) * 512 + q]) = pv;
            } else {
                __bf16* dst = (sel == 0) ? Qb : Kb;
#pragma unroll
                for (int j = 0; j < 4; ++j)
                    dst[((size_t)bh * 512 + q + j) * 64 + d] = tobf(v[j]);
            }
        }
    }
}

// ---------------- kernel 2: attention, pipelined, registers-only scores -----
// Block 256 thr = 4 waves = 2 q-tiles x 2 k-splits; per wave 16 q x 256 k.
// bias tile as MFMA C-in (Q pre-scaled 1/8); exp without max-subtract; split-K
// merge by addition. bias prefetch 3-deep (cold stream), K/V 2-deep.
__global__ __launch_bounds__(256) void attn_kernel(
    const __bf16* __restrict__ Qb, const __bf16* __restrict__ Kb,
    const __bf16* __restrict__ Vt, const float* __restrict__ bias,
    float* __restrict__ out)
{
    __shared__ __bf16 P[4][16][40];       // per-wave P slab, rows padded to 80B
    __shared__ float  Obuf[2][16][68];
    __shared__ float  Lbuf[2][16];

    const int tid = threadIdx.x, lane = tid & 63, wave = tid >> 6;
    const int lo = lane & 15, hi = lane >> 4;
    const int qt = wave >> 1, kp = wave & 1;

    int flat = blockIdx.x;
    flat = (flat & 7) * 96 + (flat >> 3);   // XCD swizzle
    const int bh = flat >> 4, qtile = flat & 15;
    const int b = bh / 12, hd = bh % 12;
    const int q0 = qtile * 32 + qt * 16;

    const __bf16* Qp = Qb + ((size_t)bh * 512 + q0) * 64;
    bf16x8 qf0 = *reinterpret_cast<const bf16x8*>(Qp + lo * 64 + hi * 8);
    bf16x8 qf1 = *reinterpret_cast<const bf16x8*>(Qp + lo * 64 + 32 + hi * 8);

    const __bf16* Kbh = Kb + (size_t)bh * 512 * 64;
    const __bf16* Vbh = Vt + (size_t)bh * 64 * 512;
    const float*  bp  = bias + ((size_t)bh * 1024 + q0) * 1024;

    f32x4 c0[3], c1[3];                   // bias: 3 stages
    bf16x8 kf[2][4], vf[2][4];            // K/V: 2 stages
    auto LOADB = [&](int kc, int s) {
        const int k0 = kp * 256 + kc * 32;
#pragma unroll
        for (int j = 0; j < 4; ++j) {
            const float* r = bp + (size_t)(hi * 4 + j) * 1024 + k0;
            c0[s][j] = r[lo];
            c1[s][j] = r[16 + lo];
        }
    };
    auto LOADKV = [&](int kc, int s) {
        const int k0 = kp * 256 + kc * 32;
        const __bf16* kr = Kbh + (size_t)(k0 + lo) * 64 + hi * 8;
        kf[s][0] = *reinterpret_cast<const bf16x8*>(kr);
        kf[s][1] = *reinterpret_cast<const bf16x8*>(kr + 32);
        kf[s][2] = *reinterpret_cast<const bf16x8*>(kr + 16 * 64);
        kf[s][3] = *reinterpret_cast<const bf16x8*>(kr + 16 * 64 + 32);
#pragma unroll
        for (int dt = 0; dt < 4; ++dt)
            vf[s][dt] = *reinterpret_cast<const bf16x8*>(
                Vbh + (size_t)(dt * 16 + lo) * 512 + k0 + hi * 8);
    };

    f32x4 oacc[4] = {};
    float lsum[4] = {0.f, 0.f, 0.f, 0.f};
    __bf16* Pw = &P[wave][0][0];

    LOADB(0, 0); LOADB(1, 1); LOADB(2, 2);
    LOADKV(0, 0);
#pragma unroll
    for (int kc = 0; kc < 8; ++kc) {
        const int sb = kc % 3, sk = kc & 1;
        if (kc < 7) LOADKV(kc + 1, sk ^ 1);   // next chunk K/V in flight
        __builtin_amdgcn_s_setprio(1);
        f32x4 s0 = __builtin_amdgcn_mfma_f32_16x16x32_bf16(qf0, kf[sk][0], c0[sb], 0, 0, 0);
        s0       = __builtin_amdgcn_mfma_f32_16x16x32_bf16(qf1, kf[sk][1], s0, 0, 0, 0);
        f32x4 s1 = __builtin_amdgcn_mfma_f32_16x16x32_bf16(qf0, kf[sk][2], c1[sb], 0, 0, 0);
        s1       = __builtin_amdgcn_mfma_f32_16x16x32_bf16(qf1, kf[sk][3], s1, 0, 0, 0);
        __builtin_amdgcn_s_setprio(0);
        if (kc < 5) LOADB(kc + 3, sb);        // bias 3 chunks ahead (stage just freed)

#pragma unroll
        for (int j = 0; j < 4; ++j) {
            float p0 = __expf(s0[j]), p1 = __expf(s1[j]);
            lsum[j] += p0 + p1;
            Pw[(hi * 4 + j) * 40 + lo]      = tobf(p0);
            Pw[(hi * 4 + j) * 40 + 16 + lo] = tobf(p1);
        }
        bf16x8 pf = *reinterpret_cast<const bf16x8*>(Pw + lo * 40 + hi * 8);
        __builtin_amdgcn_s_setprio(1);
#pragma unroll
        for (int dt = 0; dt < 4; ++dt)
            oacc[dt] = __builtin_amdgcn_mfma_f32_16x16x32_bf16(pf, vf[sk][dt], oacc[dt], 0, 0, 0);
        __builtin_amdgcn_s_setprio(0);
    }

    // reduce partial row-sums across 16-lane column groups
#pragma unroll
    for (int j = 0; j < 4; ++j) {
        float s = lsum[j];
        s += __shfl_xor(s, 1, 64); s += __shfl_xor(s, 2, 64);
        s += __shfl_xor(s, 4, 64); s += __shfl_xor(s, 8, 64);
        lsum[j] = s;
    }

    if (kp == 1) {
#pragma unroll
        for (int dt = 0; dt < 4; ++dt)
#pragma unroll
            for (int j = 0; j < 4; ++j)
                Obuf[qt][hi * 4 + j][dt * 16 + lo] = oacc[dt][j];
        if (lo == 0) {
#pragma unroll
            for (int j = 0; j < 4; ++j) Lbuf[qt][hi * 4 + j] = lsum[j];
        }
    }
    __syncthreads();
    if (kp == 0) {
#pragma unroll
        for (int j = 0; j < 4; ++j) {
            float inv = 1.0f / (lsum[j] + Lbuf[qt][hi * 4 + j]);
            int q = q0 + hi * 4 + j;
            float* op = out + (size_t)(b * 512 + q) * 768 + hd * 64;
#pragma unroll
            for (int dt = 0; dt < 4; ++dt)
                op[dt * 16 + lo] = (oacc[dt][j] + Obuf[qt][hi * 4 + j][dt * 16 + lo]) * inv;
        }
    }
}

// ---------------------------------------------------------------------------
extern "C" void kernel_launch(void* const* d_in, const int* in_sizes, int n_in,
                              void* d_out, int out_size, void* d_ws, size_t ws_size,
                              hipStream_t stream) {
    const float* hid  = (const float*)d_in[0];   // (2048,768) f32
    const float* W    = (const float*)d_in[1];   // (2304,768) f32
    const float* qb   = (const float*)d_in[2];   // (2304,) f32
    const float* bias = (const float*)d_in[3];   // (4,12,1024,1024) f32
    float* out = (float*)d_out;                  // (2048,768) f32

    char* ws = (char*)d_ws;
    __bf16* hidB = (__bf16*)(ws);                 // 3,145,728 B
    __bf16* WB   = (__bf16*)(ws + 3145728);       // 3,538,944 B
    __bf16* Qb   = (__bf16*)(ws + 6684672);       // 3,145,728 B (pre-scaled by 1/8)
    __bf16* Kb   = (__bf16*)(ws + 9830400);       // 3,145,728 B
    __bf16* Vt   = (__bf16*)(ws + 12976128);      // 3,145,728 B [bh][64][512]

    cvt_bf16<<<1632, 256, 0, stream>>>(hid, W, hidB, WB);
    qkv_gemm<<<288, 256, 0, stream>>>(hidB, WB, qb, Qb, Kb, Vt);
    attn_kernel<<<768, 256, 0, stream>>>(Qb, Kb, Vt, bias, out);
}